// Round 3
// baseline (149.876 us; speedup 1.0000x reference)
//
#include <hip/hip_runtime.h>
#include <stdint.h>

// Quant3Linear GEMV: y = x @ (scales.T * unpack3(qweight) - zeros.T) + bias
//   x: (1, 8192) f32 | qweight: (768, 28672) i32 | scales,zeros: (28672,1) | bias: (28672,)
// Decomposition: y[o] = scales[o]*dot(x, q[:,o]) - zeros[o]*sum(x) + bias[o]
//
// Stage A (q3_partial): split-K=32, 4 cols/thread via dwordx4 nt loads.
//   128-thread blocks, grid 56x32 = 1792 blocks = exactly 7 blocks/CU on 256
//   CUs -> no block-count quantization tail (896x4-wave blocks gave 3.5/CU,
//   a ~14% makespan penalty on the memory-bound phase).
// Stage B (q3_finish): 32-way partial reduce + bias - zeros*sum(x).

constexpr int O_FEAT  = 28672;
constexpr int IN_FEAT = 8192;
constexpr int NGROUP  = IN_FEAT / 32;   // 256 groups (3 packed int32 rows each)
constexpr int SPLIT   = 32;             // split-K factor
constexpr int GPB     = NGROUP / SPLIT; // 8 groups per thread
constexpr int O4      = O_FEAT / 4;     // uint4 columns per packed row (7168)

typedef uint32_t uint32x4 __attribute__((ext_vector_type(4)));
typedef float    floatx4  __attribute__((ext_vector_type(4)));

// Unpack one column-group (32 3-bit codes in w0,w1,w2; GPTQ packing) and
// accumulate dot with xv[0..31]. 3 internal chains cover FMA latency.
__device__ __forceinline__ void dot_group(uint32_t w0, uint32_t w1, uint32_t w2,
                                          const float xv[32], float& acc) {
  float a0 = acc, a1 = 0.f, a2 = 0.f;
  #pragma unroll
  for (int j = 0; j < 10; ++j) a0 += xv[j] * (float)((w0 >> (3 * j)) & 7u);
  a0 += xv[10] * (float)((w0 >> 30) | ((w1 & 1u) << 2));
  #pragma unroll
  for (int j = 0; j < 10; ++j) a1 += xv[11 + j] * (float)((w1 >> (3 * j + 1)) & 7u);
  a1 += xv[21] * (float)((w1 >> 31) | ((w2 & 3u) << 1));
  #pragma unroll
  for (int j = 0; j < 10; ++j) a2 += xv[22 + j] * (float)((w2 >> (3 * j + 2)) & 7u);
  acc = a0 + (a1 + a2);
}

__global__ __launch_bounds__(128) void q3_partial(const float* __restrict__ x,
                                                  const uint32x4* __restrict__ qw4,
                                                  floatx4* __restrict__ part) {
  const int tcol4 = blockIdx.x * 128 + threadIdx.x;  // index in units of 4 columns
  const int g0    = blockIdx.y * GPB;
  const uint32x4* qp = qw4 + (size_t)(3 * g0) * O4 + tcol4;
  const float*    xp = x + g0 * 32;                  // block-uniform -> s_load path
  float acc0 = 0.f, acc1 = 0.f, acc2 = 0.f, acc3 = 0.f;

  for (int g = 0; g < GPB; ++g) {
    // Streaming weights: zero reuse -> nontemporal to spare L2 for x/partials.
    uint32x4 wa = __builtin_nontemporal_load(qp);          // row 3g   : word0
    uint32x4 wb = __builtin_nontemporal_load(qp + O4);     // row 3g+1 : word1
    uint32x4 wc = __builtin_nontemporal_load(qp + 2 * O4); // row 3g+2 : word2
    qp += 3 * O4;

    float xv[32];
    const float4* x4 = reinterpret_cast<const float4*>(xp);
    #pragma unroll
    for (int u = 0; u < 8; ++u) {
      float4 t = x4[u];
      xv[4 * u + 0] = t.x; xv[4 * u + 1] = t.y;
      xv[4 * u + 2] = t.z; xv[4 * u + 3] = t.w;
    }
    xp += 32;

    dot_group(wa.x, wb.x, wc.x, xv, acc0);  // 4 independent chains
    dot_group(wa.y, wb.y, wc.y, xv, acc1);
    dot_group(wa.z, wb.z, wc.z, xv, acc2);
    dot_group(wa.w, wb.w, wc.w, xv, acc3);
  }

  floatx4 r = {acc0, acc1, acc2, acc3};
  part[(size_t)blockIdx.y * O4 + tcol4] = r;
}

__global__ __launch_bounds__(256) void q3_finish(const float* __restrict__ x,
                                                 const float* __restrict__ part,
                                                 const float* __restrict__ scales,
                                                 const float* __restrict__ zeros,
                                                 const float* __restrict__ bias,
                                                 float* __restrict__ out) {
  // Block-redundant reduction of x (32 KB, L2-resident).
  float s = 0.f;
  const float4* x4 = reinterpret_cast<const float4*>(x);
  for (int i = threadIdx.x; i < IN_FEAT / 4; i += 256) {
    float4 t = x4[i];
    s += (t.x + t.y) + (t.z + t.w);
  }
  #pragma unroll
  for (int off = 32; off > 0; off >>= 1) s += __shfl_down(s, off, 64);
  __shared__ float ls[4];
  if ((threadIdx.x & 63) == 0) ls[threadIdx.x >> 6] = s;
  __syncthreads();
  float S = (ls[0] + ls[1]) + (ls[2] + ls[3]);

  int o = blockIdx.x * 256 + threadIdx.x;
  float sum = 0.f;
  #pragma unroll
  for (int y = 0; y < SPLIT; ++y) sum += part[(size_t)y * O_FEAT + o];
  out[o] = scales[o] * sum - zeros[o] * S + bias[o];
}

extern "C" void kernel_launch(void* const* d_in, const int* in_sizes, int n_in,
                              void* d_out, int out_size, void* d_ws, size_t ws_size,
                              hipStream_t stream) {
  const float*    x      = (const float*)d_in[0];
  const uint32x4* qw4    = (const uint32x4*)d_in[1];
  const float*    scales = (const float*)d_in[2];
  const float*    zeros  = (const float*)d_in[3];
  const float*    bias   = (const float*)d_in[4];
  float*          out    = (float*)d_out;
  floatx4*        part   = (floatx4*)d_ws;   // SPLIT * O_FEAT floats = 3.67 MB

  q3_partial<<<dim3(O4 / 128, SPLIT), dim3(128), 0, stream>>>(x, qw4, part);
  q3_finish<<<dim3(O_FEAT / 256), dim3(256), 0, stream>>>(x, (const float*)part,
                                                          scales, zeros, bias, out);
}

// Round 4
// 145.294 us; speedup vs baseline: 1.0315x; 1.0315x over previous
//
#include <hip/hip_runtime.h>
#include <stdint.h>

// Quant3Linear GEMV: y = x @ (scales.T * unpack3(qweight) - zeros.T) + bias
//   x: (1, 8192) f32 | qweight: (768, 28672) i32 | scales,zeros: (28672,1) | bias: (28672,)
// Decomposition: y[o] = scales[o]*dot(x, q[:,o]) - zeros[o]*sum(x) + bias[o]
//
// Stage A (q3_partial): split-K=32, 4 cols/thread via dwordx4 loads (PLAIN,
//   not nontemporal -- nt regressed R3), 128-thread blocks -> 1792 blocks =
//   exactly 7/CU, explicit 1-deep weight prefetch so each wave holds the next
//   group's 48 B/lane in flight while computing the current group.
// Stage B (q3_finish): 32-way partial reduce + bias - zeros*sum(x).

constexpr int O_FEAT  = 28672;
constexpr int IN_FEAT = 8192;
constexpr int NGROUP  = IN_FEAT / 32;   // 256 groups (3 packed int32 rows each)
constexpr int SPLIT   = 32;             // split-K factor
constexpr int GPB     = NGROUP / SPLIT; // 8 groups per thread
constexpr int O4      = O_FEAT / 4;     // uint4 columns per packed row (7168)

typedef uint32_t uint32x4 __attribute__((ext_vector_type(4)));
typedef float    floatx4  __attribute__((ext_vector_type(4)));

// Unpack one column-group (32 3-bit codes in w0,w1,w2; GPTQ packing) and
// accumulate dot with xv[0..31]. 3 internal chains cover FMA latency.
__device__ __forceinline__ void dot_group(uint32_t w0, uint32_t w1, uint32_t w2,
                                          const float xv[32], float& acc) {
  float a0 = acc, a1 = 0.f, a2 = 0.f;
  #pragma unroll
  for (int j = 0; j < 10; ++j) a0 += xv[j] * (float)((w0 >> (3 * j)) & 7u);
  a0 += xv[10] * (float)((w0 >> 30) | ((w1 & 1u) << 2));
  #pragma unroll
  for (int j = 0; j < 10; ++j) a1 += xv[11 + j] * (float)((w1 >> (3 * j + 1)) & 7u);
  a1 += xv[21] * (float)((w1 >> 31) | ((w2 & 3u) << 1));
  #pragma unroll
  for (int j = 0; j < 10; ++j) a2 += xv[22 + j] * (float)((w2 >> (3 * j + 2)) & 7u);
  acc = a0 + (a1 + a2);
}

__global__ __launch_bounds__(128) void q3_partial(const float* __restrict__ x,
                                                  const uint32x4* __restrict__ qw4,
                                                  floatx4* __restrict__ part) {
  const int tcol4 = blockIdx.x * 128 + threadIdx.x;  // index in units of 4 columns
  const int g0    = blockIdx.y * GPB;
  const uint32x4* qp = qw4 + (size_t)(3 * g0) * O4 + tcol4;
  const float*    xp = x + g0 * 32;                  // block-uniform address
  float acc0 = 0.f, acc1 = 0.f, acc2 = 0.f, acc3 = 0.f;

  // Prologue: first group's weights in flight before the loop.
  uint32x4 wa = qp[0];
  uint32x4 wb = qp[O4];
  uint32x4 wc = qp[2 * O4];

  #pragma unroll
  for (int g = 0; g < GPB; ++g) {
    // Prefetch next group's weights (guard folds away under full unroll).
    uint32x4 na = {0, 0, 0, 0}, nb = {0, 0, 0, 0}, nc = {0, 0, 0, 0};
    qp += 3 * O4;
    if (g < GPB - 1) {
      na = qp[0];
      nb = qp[O4];
      nc = qp[2 * O4];
    }

    float xv[32];
    const float4* x4 = reinterpret_cast<const float4*>(xp);
    #pragma unroll
    for (int u = 0; u < 8; ++u) {
      float4 t = x4[u];
      xv[4 * u + 0] = t.x; xv[4 * u + 1] = t.y;
      xv[4 * u + 2] = t.z; xv[4 * u + 3] = t.w;
    }
    xp += 32;

    dot_group(wa.x, wb.x, wc.x, xv, acc0);  // 4 independent chains
    dot_group(wa.y, wb.y, wc.y, xv, acc1);
    dot_group(wa.z, wb.z, wc.z, xv, acc2);
    dot_group(wa.w, wb.w, wc.w, xv, acc3);

    wa = na; wb = nb; wc = nc;
  }

  floatx4 r = {acc0, acc1, acc2, acc3};
  part[(size_t)blockIdx.y * O4 + tcol4] = r;
}

__global__ __launch_bounds__(256) void q3_finish(const float* __restrict__ x,
                                                 const float* __restrict__ part,
                                                 const float* __restrict__ scales,
                                                 const float* __restrict__ zeros,
                                                 const float* __restrict__ bias,
                                                 float* __restrict__ out) {
  // Block-redundant reduction of x (32 KB, L2-resident).
  float s = 0.f;
  const float4* x4 = reinterpret_cast<const float4*>(x);
  for (int i = threadIdx.x; i < IN_FEAT / 4; i += 256) {
    float4 t = x4[i];
    s += (t.x + t.y) + (t.z + t.w);
  }
  #pragma unroll
  for (int off = 32; off > 0; off >>= 1) s += __shfl_down(s, off, 64);
  __shared__ float ls[4];
  if ((threadIdx.x & 63) == 0) ls[threadIdx.x >> 6] = s;
  __syncthreads();
  float S = (ls[0] + ls[1]) + (ls[2] + ls[3]);

  int o = blockIdx.x * 256 + threadIdx.x;
  float sum = 0.f;
  #pragma unroll
  for (int y = 0; y < SPLIT; ++y) sum += part[(size_t)y * O_FEAT + o];
  out[o] = scales[o] * sum - zeros[o] * S + bias[o];
}

extern "C" void kernel_launch(void* const* d_in, const int* in_sizes, int n_in,
                              void* d_out, int out_size, void* d_ws, size_t ws_size,
                              hipStream_t stream) {
  const float*    x      = (const float*)d_in[0];
  const uint32x4* qw4    = (const uint32x4*)d_in[1];
  const float*    scales = (const float*)d_in[2];
  const float*    zeros  = (const float*)d_in[3];
  const float*    bias   = (const float*)d_in[4];
  float*          out    = (float*)d_out;
  floatx4*        part   = (floatx4*)d_ws;   // SPLIT * O_FEAT floats = 3.67 MB

  q3_partial<<<dim3(O4 / 128, SPLIT), dim3(128), 0, stream>>>(x, qw4, part);
  q3_finish<<<dim3(O_FEAT / 256), dim3(256), 0, stream>>>(x, (const float*)part,
                                                          scales, zeros, bias, out);
}